// Round 2
// baseline (249.996 us; speedup 1.0000x reference)
//
#include <hip/hip_runtime.h>
#include <math.h>

#define NQ 8
#define FDIM 2048
#define EPSV 1e-5f

// Block: 1024 threads = 256 tokens x 4 k-quarters. Grid: ntok/256 = 256 blocks.
// Weights are read with wave-uniform indices straight from global memory so the
// compiler can scalarize them to s_load (SMEM pipe) -> DS pipe stays idle.
// Round-1 evidence: 34816 broadcast ds_read_b128/CU at ~10 cyc each == the
// entire 145us runtime; broadcast LDS reads get no return-path discount.
__launch_bounds__(1024, 4)
__global__ void qtb_kernel(const float* __restrict__ x,
                           const float* __restrict__ theta,
                           const float* __restrict__ phi,
                           const float* __restrict__ W1,
                           const float* __restrict__ b1,
                           const float* __restrict__ W2,
                           const float* __restrict__ b2,
                           const float* __restrict__ g1,
                           const float* __restrict__ be1,
                           const float* __restrict__ g2,
                           const float* __restrict__ be2,
                           float* __restrict__ out)
{
    __shared__ float buf[512 * NQ];   // 16 KB combine buffer for the k-split tree

    const int tid   = threadIdx.x;
    const int q     = tid >> 8;        // k-quarter 0..3
    const int slot  = tid & 255;       // token within block
    const int token = blockIdx.x * 256 + slot;

    // ---- load token (divergent -> vector loads, coalesced) ----
    const float4 xa = reinterpret_cast<const float4*>(x + (size_t)token * NQ)[0];
    const float4 xb = reinterpret_cast<const float4*>(x + (size_t)token * NQ)[1];
    float xv[8] = {xa.x, xa.y, xa.z, xa.w, xb.x, xb.y, xb.z, xb.w};

    // ---- attention closed form: c_j = cos(x_j+theta_j);
    //      attn_0 = prod_{j=1..7} c_j; attn_i = prod_{j<=i} c_j ----
    float c[8];
#pragma unroll
    for (int j = 0; j < 8; ++j) c[j] = cosf(xv[j] + theta[j]);

    float attn[8];
    attn[0] = ((c[1] * c[2]) * (c[3] * c[4])) * ((c[5] * c[6]) * c[7]);
    {
        float p = c[0];
#pragma unroll
        for (int j = 1; j < 8; ++j) { p *= c[j]; attn[j] = p; }
    }

    // ---- layernorm1(x + attn) ----
    float s[8];
#pragma unroll
    for (int j = 0; j < 8; ++j) s[j] = xv[j] + attn[j];
    float mean = 0.f;
#pragma unroll
    for (int j = 0; j < 8; ++j) mean += s[j];
    mean *= 0.125f;
    float var = 0.f;
#pragma unroll
    for (int j = 0; j < 8; ++j) { float d = s[j] - mean; var = fmaf(d, d, var); }
    var *= 0.125f;
    float rs = rsqrtf(var + EPSV);
    float h[8];
#pragma unroll
    for (int j = 0; j < 8; ++j) h[j] = (s[j] - mean) * rs * g1[j] + be1[j];

    // ---- ffn_quantum closed form: z_j = cos(phi_j) * cos(h_j) ----
    float zv[8];
#pragma unroll
    for (int j = 0; j < 8; ++j) zv[j] = cosf(phi[j]) * cosf(h[j]);

    // ---- FFN quarter: k in [q*512, q*512+512) ----
    // t_k = relu(b1_k + sum_j z_j W1[k][j]); acc_i += t_k * W2[i][k]
    // All weight indices are wave-uniform -> scalar loads.
    float acc[8] = {0.f, 0.f, 0.f, 0.f, 0.f, 0.f, 0.f, 0.f};
    const int k0 = q * 512;

    for (int kk = 0; kk < 512; kk += 4) {
        const int k = k0 + kk;
        float t[4];
#pragma unroll
        for (int m = 0; m < 4; ++m) {
            const float* __restrict__ w = W1 + (size_t)(k + m) * NQ;
            float u = b1[k + m];
            u = fmaf(w[0], zv[0], u);
            u = fmaf(w[1], zv[1], u);
            u = fmaf(w[2], zv[2], u);
            u = fmaf(w[3], zv[3], u);
            u = fmaf(w[4], zv[4], u);
            u = fmaf(w[5], zv[5], u);
            u = fmaf(w[6], zv[6], u);
            u = fmaf(w[7], zv[7], u);
            t[m] = fmaxf(u, 0.f);
        }
#pragma unroll
        for (int i = 0; i < 8; ++i) {
            const float* __restrict__ w2r = W2 + (size_t)i * FDIM + k;
            float a2 = acc[i];
            a2 = fmaf(t[0], w2r[0], a2);
            a2 = fmaf(t[1], w2r[1], a2);
            a2 = fmaf(t[2], w2r[2], a2);
            a2 = fmaf(t[3], w2r[3], a2);
            acc[i] = a2;
        }
    }

    // ---- combine the 4 quarter-partials (LDS tree, 16 KB) ----
    // stage A: quarters 2,3 park partials; quarters 0,1 add them.
    if (tid >= 512) {
        float* b = &buf[(tid - 512) * NQ];
#pragma unroll
        for (int i = 0; i < 8; ++i) b[i] = acc[i];
    }
    __syncthreads();
    if (tid < 512) {
        const float* b = &buf[tid * NQ];
#pragma unroll
        for (int i = 0; i < 8; ++i) acc[i] += b[i];
    }
    __syncthreads();
    // stage B: quarter 1 parks; quarter 0 finishes.
    if (tid >= 256 && tid < 512) {
        float* b = &buf[(tid - 256) * NQ];
#pragma unroll
        for (int i = 0; i < 8; ++i) b[i] = acc[i];
    }
    __syncthreads();
    if (tid < 256) {
        const float* b = &buf[tid * NQ];
#pragma unroll
        for (int i = 0; i < 8; ++i) acc[i] += b[i];

        // ---- layernorm2(h + f) + store ----
        float y[8];
#pragma unroll
        for (int j = 0; j < 8; ++j) y[j] = h[j] + acc[j] + b2[j];
        float mean2 = 0.f;
#pragma unroll
        for (int j = 0; j < 8; ++j) mean2 += y[j];
        mean2 *= 0.125f;
        float var2 = 0.f;
#pragma unroll
        for (int j = 0; j < 8; ++j) { float d = y[j] - mean2; var2 = fmaf(d, d, var2); }
        var2 *= 0.125f;
        float rs2 = rsqrtf(var2 + EPSV);

        float o[8];
#pragma unroll
        for (int j = 0; j < 8; ++j) o[j] = (y[j] - mean2) * rs2 * g2[j] + be2[j];

        float4* op = reinterpret_cast<float4*>(out + (size_t)token * NQ);
        op[0] = make_float4(o[0], o[1], o[2], o[3]);
        op[1] = make_float4(o[4], o[5], o[6], o[7]);
    }
}

extern "C" void kernel_launch(void* const* d_in, const int* in_sizes, int n_in,
                              void* d_out, int out_size, void* d_ws, size_t ws_size,
                              hipStream_t stream) {
    const float* x     = (const float*)d_in[0];
    const float* theta = (const float*)d_in[1];
    const float* phi   = (const float*)d_in[2];
    const float* W1    = (const float*)d_in[3];
    const float* b1    = (const float*)d_in[4];
    const float* W2    = (const float*)d_in[5];
    const float* b2    = (const float*)d_in[6];
    const float* g1    = (const float*)d_in[7];
    const float* be1   = (const float*)d_in[8];
    const float* g2    = (const float*)d_in[9];
    const float* be2   = (const float*)d_in[10];
    float* out = (float*)d_out;

    const int ntok = in_sizes[0] / NQ;          // 65536
    const int grid = ntok / 256;                // 256 blocks, 1024 threads each

    qtb_kernel<<<grid, 1024, 0, stream>>>(x, theta, phi, W1, b1, W2, b2,
                                          g1, be1, g2, be2, out);
}

// Round 3
// 32.410 us; speedup vs baseline: 7.7136x; 7.7136x over previous
//
#include <hip/hip_runtime.h>
#include <math.h>

#define NQ 8
#define FDIM 2048
#define EPSV 1e-5f

typedef __attribute__((ext_vector_type(8))) short short8v;   // 8 bf16 = 4 VGPR
typedef __attribute__((ext_vector_type(16))) float f32x16;   // 32x32 C/D frag

union PackU { unsigned u[4]; short8v s; };

__device__ __forceinline__ unsigned pk_bf16(float lo, float hi) {
    unsigned r;
    asm("v_cvt_pk_bf16_f32 %0, %1, %2" : "=v"(r) : "v"(lo), "v"(hi));
    return r;
}

// Block: 256 thr = 4 waves; wave owns 64 tokens (2 subtiles of 32).
// GEMM1: tT[32k x 32tok] = W1b[32k x 16(9 used)] @ zbT[16 x 32tok]  (1 MFMA/subtile/chunk)
// GEMM2: out[32tok x 32(8 used)] += t[32tok x 16k] @ W2T[16k x 32]  (2 MFMA/subtile/chunk)
// C1 regs feed GEMM2 A-frags identically (double-K layout) -> repack = relu + cvt_pk only.
__launch_bounds__(256, 1)
__global__ void qtb_kernel(const float* __restrict__ x,
                           const float* __restrict__ theta,
                           const float* __restrict__ phi,
                           const float* __restrict__ W1,
                           const float* __restrict__ b1,
                           const float* __restrict__ W2,
                           const float* __restrict__ b2,
                           const float* __restrict__ g1,
                           const float* __restrict__ be1,
                           const float* __restrict__ g2,
                           const float* __restrict__ be2,
                           float* __restrict__ out)
{
    __shared__ short W1f[64 * 512];    // 64 chunks x (64 lanes x 8 bf16), A-frag order, 64 KB
    __shared__ short W2s[8 * 2056];    // bf16, quad-permuted k, padded rows, ~33 KB
    __shared__ float fbuf[4][64 * 8];  // per-wave f staging for epilogue, 8 KB

    const int tid = threadIdx.x;

    // ---- stage W1(+b1) into A-fragment order ----
    // lane (k&31, hi2=0): [w0..w3, b1, 0,0,0]; lane (+32, hi2=1): [w4..w7, 0,0,0,0]
    for (int k = tid; k < FDIM; k += 256) {
        const float4 wa = *reinterpret_cast<const float4*>(W1 + (size_t)k * NQ);
        const float4 wb = *reinterpret_cast<const float4*>(W1 + (size_t)k * NQ + 4);
        const float bk = b1[k];
        unsigned* d0 = reinterpret_cast<unsigned*>(&W1f[(k >> 5) * 512 + (k & 31) * 8]);
        unsigned* d1 = reinterpret_cast<unsigned*>(&W1f[(k >> 5) * 512 + ((k & 31) + 32) * 8]);
        d0[0] = pk_bf16(wa.x, wa.y); d0[1] = pk_bf16(wa.z, wa.w);
        d0[2] = pk_bf16(bk, 0.f);    d0[3] = 0u;
        d1[0] = pk_bf16(wb.x, wb.y); d1[1] = pk_bf16(wb.z, wb.w);
        d1[2] = 0u;                  d1[3] = 0u;
    }
    // ---- stage W2 bf16; permute k within each 16-block (quad order 0,2,1,3) so
    //      B-frags are 16B-contiguous: hi2 half h reads [4h..4h+3, 8+4h..8+4h+3] ----
    for (int idx = tid; idx < 8 * 1024; idx += 256) {
        const int i = idx >> 10, kp = idx & 1023;
        const int k0 = kp * 2;
        const float2 w = *reinterpret_cast<const float2*>(W2 + (size_t)i * FDIM + k0);
        const int quad = (k0 >> 2) & 3;
        const int posq = (0x3120 >> (quad * 4)) & 0xF;   // 0->0, 1->2, 2->1, 3->3
        const int dcol = (k0 & ~15) | (posq * 4 + (k0 & 3));
        *reinterpret_cast<unsigned*>(&W2s[i * 2056 + dcol]) = pk_bf16(w.x, w.y);
    }
    __syncthreads();

    const int lane = tid & 63;
    const int wid  = tid >> 6;
    const int hi2  = lane >> 5;
    const int il   = lane & 31;
    const int token = blockIdx.x * 256 + wid * 64 + lane;

    // ---- per-token prologue (token-per-lane, 64 tokens/wave) ----
    const float4 xa = reinterpret_cast<const float4*>(x + (size_t)token * NQ)[0];
    const float4 xb = reinterpret_cast<const float4*>(x + (size_t)token * NQ)[1];
    float xv[8] = {xa.x, xa.y, xa.z, xa.w, xb.x, xb.y, xb.z, xb.w};

    float c[8];
#pragma unroll
    for (int j = 0; j < 8; ++j) c[j] = cosf(xv[j] + theta[j]);
    float attn[8];
    attn[0] = ((c[1] * c[2]) * (c[3] * c[4])) * ((c[5] * c[6]) * c[7]);
    {
        float p = c[0];
#pragma unroll
        for (int j = 1; j < 8; ++j) { p *= c[j]; attn[j] = p; }
    }
    float s[8];
#pragma unroll
    for (int j = 0; j < 8; ++j) s[j] = xv[j] + attn[j];
    float mean = 0.f;
#pragma unroll
    for (int j = 0; j < 8; ++j) mean += s[j];
    mean *= 0.125f;
    float var = 0.f;
#pragma unroll
    for (int j = 0; j < 8; ++j) { float d = s[j] - mean; var = fmaf(d, d, var); }
    var *= 0.125f;
    const float rs = rsqrtf(var + EPSV);
    float h[8];
#pragma unroll
    for (int j = 0; j < 8; ++j) h[j] = (s[j] - mean) * rs * g1[j] + be1[j];

    float zv[8];
#pragma unroll
    for (int j = 0; j < 8; ++j) zv[j] = cosf(phi[j]) * cosf(h[j]);

    // ---- build z B-fragments for both token-subtiles ----
    unsigned zpk[4];
#pragma unroll
    for (int p = 0; p < 4; ++p) zpk[p] = pk_bf16(zv[2 * p], zv[2 * p + 1]);
    unsigned zApk[4], zBpk[4];
#pragma unroll
    for (int p = 0; p < 4; ++p) {
        zApk[p] = (unsigned)__shfl((int)zpk[p], il);        // tokens base+0..31
        zBpk[p] = (unsigned)__shfl((int)zpk[p], 32 + il);   // tokens base+32..63
    }
    // B1 frag: k' = 4*hi2 + (e&3) + 8*(e>>2); k'<8 -> z, k'=8 -> 1.0 (bias), else 0
    const unsigned biasv = 0x00003f80u;  // bf16(1.0) in low half
    PackU b1A, b1B;
    b1A.u[0] = hi2 ? zApk[2] : zApk[0];
    b1A.u[1] = hi2 ? zApk[3] : zApk[1];
    b1A.u[2] = hi2 ? 0u : biasv;
    b1A.u[3] = 0u;
    b1B.u[0] = hi2 ? zBpk[2] : zBpk[0];
    b1B.u[1] = hi2 ? zBpk[3] : zBpk[1];
    b1B.u[2] = hi2 ? 0u : biasv;
    b1B.u[3] = 0u;

    f32x16 zeroC;
#pragma unroll
    for (int e = 0; e < 16; ++e) zeroC[e] = 0.f;
    f32x16 accA = zeroC, accB = zeroC;

    const int ir = il & 7;  // B2 rows 8..31 duplicate rows 0..7 (cols ignored)

    // ---- fused k-loop: 64 chunks of 32k, all wave-local, no barriers ----
#pragma unroll 2
    for (int cc = 0; cc < 64; ++cc) {
        const short8v A1 = *reinterpret_cast<const short8v*>(&W1f[cc * 512 + lane * 8]);
        f32x16 C1A = __builtin_amdgcn_mfma_f32_32x32x16_bf16(A1, b1A.s, zeroC, 0, 0, 0);
        f32x16 C1B = __builtin_amdgcn_mfma_f32_32x32x16_bf16(A1, b1B.s, zeroC, 0, 0, 0);

        const short* w2base = &W2s[ir * 2056 + cc * 32];
        const short8v B2w0 = *reinterpret_cast<const short8v*>(w2base + hi2 * 8);
        const short8v B2w1 = *reinterpret_cast<const short8v*>(w2base + 16 + hi2 * 8);

        // relu + bf16-pack; C1 regs are already in A-frag order (double-K layout)
        PackU a0A, a1A, a0B, a1B;
#pragma unroll
        for (int v = 0; v < 4; ++v) {
            a0A.u[v] = pk_bf16(fmaxf(C1A[2 * v], 0.f),     fmaxf(C1A[2 * v + 1], 0.f));
            a1A.u[v] = pk_bf16(fmaxf(C1A[2 * v + 8], 0.f), fmaxf(C1A[2 * v + 9], 0.f));
            a0B.u[v] = pk_bf16(fmaxf(C1B[2 * v], 0.f),     fmaxf(C1B[2 * v + 1], 0.f));
            a1B.u[v] = pk_bf16(fmaxf(C1B[2 * v + 8], 0.f), fmaxf(C1B[2 * v + 9], 0.f));
        }
        accA = __builtin_amdgcn_mfma_f32_32x32x16_bf16(a0A.s, B2w0, accA, 0, 0, 0);
        accA = __builtin_amdgcn_mfma_f32_32x32x16_bf16(a1A.s, B2w1, accA, 0, 0, 0);
        accB = __builtin_amdgcn_mfma_f32_32x32x16_bf16(a0B.s, B2w0, accB, 0, 0, 0);
        accB = __builtin_amdgcn_mfma_f32_32x32x16_bf16(a1B.s, B2w1, accB, 0, 0, 0);
    }

    // ---- epilogue: park f (cols<8) in LDS, then token-per-lane LN2 ----
    if (il < 8) {
        float* fb = &fbuf[wid][0];
#pragma unroll
        for (int r = 0; r < 16; ++r) {
            const int trow = (r & 3) + 8 * (r >> 2) + 4 * hi2;
            fb[trow * 8 + il]        = accA[r];
            fb[(32 + trow) * 8 + il] = accB[r];
        }
    }
    // same-wave LDS write->read: in-order per wave, no barrier needed
    const float4 f0 = *reinterpret_cast<const float4*>(&fbuf[wid][lane * 8]);
    const float4 f1 = *reinterpret_cast<const float4*>(&fbuf[wid][lane * 8 + 4]);
    const float fv[8] = {f0.x, f0.y, f0.z, f0.w, f1.x, f1.y, f1.z, f1.w};

    float y[8];
#pragma unroll
    for (int j = 0; j < 8; ++j) y[j] = h[j] + fv[j] + b2[j];
    float mean2 = 0.f;
#pragma unroll
    for (int j = 0; j < 8; ++j) mean2 += y[j];
    mean2 *= 0.125f;
    float var2 = 0.f;
#pragma unroll
    for (int j = 0; j < 8; ++j) { float d = y[j] - mean2; var2 = fmaf(d, d, var2); }
    var2 *= 0.125f;
    const float rs2 = rsqrtf(var2 + EPSV);

    float o[8];
#pragma unroll
    for (int j = 0; j < 8; ++j) o[j] = (y[j] - mean2) * rs2 * g2[j] + be2[j];

    float4* op = reinterpret_cast<float4*>(out + (size_t)token * NQ);
    op[0] = make_float4(o[0], o[1], o[2], o[3]);
    op[1] = make_float4(o[4], o[5], o[6], o[7]);
}

extern "C" void kernel_launch(void* const* d_in, const int* in_sizes, int n_in,
                              void* d_out, int out_size, void* d_ws, size_t ws_size,
                              hipStream_t stream) {
    const float* x     = (const float*)d_in[0];
    const float* theta = (const float*)d_in[1];
    const float* phi   = (const float*)d_in[2];
    const float* W1    = (const float*)d_in[3];
    const float* b1    = (const float*)d_in[4];
    const float* W2    = (const float*)d_in[5];
    const float* b2    = (const float*)d_in[6];
    const float* g1    = (const float*)d_in[7];
    const float* be1   = (const float*)d_in[8];
    const float* g2    = (const float*)d_in[9];
    const float* be2   = (const float*)d_in[10];
    float* out = (float*)d_out;

    const int ntok = in_sizes[0] / NQ;   // 65536
    const int grid = ntok / 256;         // 256 blocks x 256 thr, 1 block/CU

    qtb_kernel<<<grid, 256, 0, stream>>>(x, theta, phi, W1, b1, W2, b2,
                                         g1, be1, g2, be2, out);
}

// Round 4
// 26.061 us; speedup vs baseline: 9.5927x; 1.2436x over previous
//
#include <hip/hip_runtime.h>
#include <math.h>

#define NQ 8
#define FDIM 2048
#define EPSV 1e-5f

typedef __attribute__((ext_vector_type(8))) short short8v;   // 8 bf16 = 4 VGPR
typedef __attribute__((ext_vector_type(16))) float f32x16;   // 32x32 C/D frag

union PackU { unsigned u[4]; short8v s; };

__device__ __forceinline__ unsigned pk_bf16(float lo, float hi) {
    unsigned r;
    asm("v_cvt_pk_bf16_f32 %0, %1, %2" : "=v"(r) : "v"(lo), "v"(hi));
    return r;
}

// 1024 thr = 16 waves = 4/SIMD (latency hiding; R3 was 1 wave/SIMD -> 10% MfmaUtil).
// wave wid = q*4+g: token group g (64 tokens), f-chunks [q*16, q*16+16).
// GEMM1 contraction (NQ+bias) lives inside one MFMA -> relu exact under f-split;
// f-chunk loop is GEMM2's contraction -> partials sum linearly (parked in LDS).
__launch_bounds__(1024, 1)
__global__ void qtb_kernel(const float* __restrict__ x,
                           const float* __restrict__ theta,
                           const float* __restrict__ phi,
                           const float* __restrict__ W1,
                           const float* __restrict__ b1,
                           const float* __restrict__ W2,
                           const float* __restrict__ b2,
                           const float* __restrict__ g1,
                           const float* __restrict__ be1,
                           const float* __restrict__ g2,
                           const float* __restrict__ be2,
                           float* __restrict__ out)
{
    __shared__ short W1f[64 * 512];    // A-frag order, 64 KB
    __shared__ short W2s[8 * 2056];    // quad-permuted k, ~33 KB
    __shared__ float park[16][512];    // per-wave partial f (64 tok x 8), 32 KB

    const int tid = threadIdx.x;

    // ---- stage W1(+b1) into A-fragment order (2 iters) ----
    for (int k = tid; k < FDIM; k += 1024) {
        const float4 wa = *reinterpret_cast<const float4*>(W1 + (size_t)k * NQ);
        const float4 wb = *reinterpret_cast<const float4*>(W1 + (size_t)k * NQ + 4);
        const float bk = b1[k];
        unsigned* d0 = reinterpret_cast<unsigned*>(&W1f[(k >> 5) * 512 + (k & 31) * 8]);
        unsigned* d1 = reinterpret_cast<unsigned*>(&W1f[(k >> 5) * 512 + ((k & 31) + 32) * 8]);
        d0[0] = pk_bf16(wa.x, wa.y); d0[1] = pk_bf16(wa.z, wa.w);
        d0[2] = pk_bf16(bk, 0.f);    d0[3] = 0u;
        d1[0] = pk_bf16(wb.x, wb.y); d1[1] = pk_bf16(wb.z, wb.w);
        d1[2] = 0u;                  d1[3] = 0u;
    }
    // ---- stage W2 bf16, k permuted in 16-blocks (quad order 0,2,1,3) (8 iters) ----
    for (int idx = tid; idx < 8 * 1024; idx += 1024) {
        const int i = idx >> 10, kp = idx & 1023;
        const int k0 = kp * 2;
        const float2 w = *reinterpret_cast<const float2*>(W2 + (size_t)i * FDIM + k0);
        const int quad = (k0 >> 2) & 3;
        const int posq = (0x3120 >> (quad * 4)) & 0xF;
        const int dcol = (k0 & ~15) | (posq * 4 + (k0 & 3));
        *reinterpret_cast<unsigned*>(&W2s[i * 2056 + dcol]) = pk_bf16(w.x, w.y);
    }
    __syncthreads();

    const int lane = tid & 63;
    const int wid  = tid >> 6;      // 0..15
    const int q    = wid >> 2;      // f-quarter 0..3
    const int g    = wid & 3;       // token group 0..3
    const int hi2  = lane >> 5;
    const int il   = lane & 31;
    const int token = blockIdx.x * 256 + g * 64 + lane;

    // ---- per-token prologue (replicated across the 4 f-quarter waves) ----
    const float4 xa = reinterpret_cast<const float4*>(x + (size_t)token * NQ)[0];
    const float4 xb = reinterpret_cast<const float4*>(x + (size_t)token * NQ)[1];
    float xv[8] = {xa.x, xa.y, xa.z, xa.w, xb.x, xb.y, xb.z, xb.w};

    float c[8];
#pragma unroll
    for (int j = 0; j < 8; ++j) c[j] = cosf(xv[j] + theta[j]);
    float attn[8];
    attn[0] = ((c[1] * c[2]) * (c[3] * c[4])) * ((c[5] * c[6]) * c[7]);
    {
        float p = c[0];
#pragma unroll
        for (int j = 1; j < 8; ++j) { p *= c[j]; attn[j] = p; }
    }
    float s[8];
#pragma unroll
    for (int j = 0; j < 8; ++j) s[j] = xv[j] + attn[j];
    float mean = 0.f;
#pragma unroll
    for (int j = 0; j < 8; ++j) mean += s[j];
    mean *= 0.125f;
    float var = 0.f;
#pragma unroll
    for (int j = 0; j < 8; ++j) { float d = s[j] - mean; var = fmaf(d, d, var); }
    var *= 0.125f;
    const float rs = rsqrtf(var + EPSV);
    float h[8];
#pragma unroll
    for (int j = 0; j < 8; ++j) h[j] = (s[j] - mean) * rs * g1[j] + be1[j];

    float zv[8];
#pragma unroll
    for (int j = 0; j < 8; ++j) zv[j] = cosf(phi[j]) * cosf(h[j]);

    // ---- z B-fragments for both token-subtiles ----
    unsigned zpk[4];
#pragma unroll
    for (int p = 0; p < 4; ++p) zpk[p] = pk_bf16(zv[2 * p], zv[2 * p + 1]);
    unsigned zApk[4], zBpk[4];
#pragma unroll
    for (int p = 0; p < 4; ++p) {
        zApk[p] = (unsigned)__shfl((int)zpk[p], il);
        zBpk[p] = (unsigned)__shfl((int)zpk[p], 32 + il);
    }
    const unsigned biasv = 0x00003f80u;  // bf16(1.0) low half
    PackU b1A, b1B;
    b1A.u[0] = hi2 ? zApk[2] : zApk[0];
    b1A.u[1] = hi2 ? zApk[3] : zApk[1];
    b1A.u[2] = hi2 ? 0u : biasv;
    b1A.u[3] = 0u;
    b1B.u[0] = hi2 ? zBpk[2] : zBpk[0];
    b1B.u[1] = hi2 ? zBpk[3] : zBpk[1];
    b1B.u[2] = hi2 ? 0u : biasv;
    b1B.u[3] = 0u;

    f32x16 zeroC;
#pragma unroll
    for (int e = 0; e < 16; ++e) zeroC[e] = 0.f;
    f32x16 accA = zeroC, accB = zeroC;

    const int ir = il & 7;

    // ---- f-chunk loop: 16 chunks of 32 f per wave ----
#pragma unroll 2
    for (int t = 0; t < 16; ++t) {
        const int cc = q * 16 + t;
        const short8v A1 = *reinterpret_cast<const short8v*>(&W1f[cc * 512 + lane * 8]);
        const short* w2base = &W2s[ir * 2056 + cc * 32];
        const short8v B2w0 = *reinterpret_cast<const short8v*>(w2base + hi2 * 8);
        const short8v B2w1 = *reinterpret_cast<const short8v*>(w2base + 16 + hi2 * 8);

        // C1A -> repack -> C1B -> repack (serialized to cap VGPR peak at <=128)
        f32x16 C1A = __builtin_amdgcn_mfma_f32_32x32x16_bf16(A1, b1A.s, zeroC, 0, 0, 0);
        PackU a0A, a1A;
#pragma unroll
        for (int v = 0; v < 4; ++v) {
            a0A.u[v] = pk_bf16(fmaxf(C1A[2 * v], 0.f),     fmaxf(C1A[2 * v + 1], 0.f));
            a1A.u[v] = pk_bf16(fmaxf(C1A[2 * v + 8], 0.f), fmaxf(C1A[2 * v + 9], 0.f));
        }
        f32x16 C1B = __builtin_amdgcn_mfma_f32_32x32x16_bf16(A1, b1B.s, zeroC, 0, 0, 0);
        PackU a0B, a1B;
#pragma unroll
        for (int v = 0; v < 4; ++v) {
            a0B.u[v] = pk_bf16(fmaxf(C1B[2 * v], 0.f),     fmaxf(C1B[2 * v + 1], 0.f));
            a1B.u[v] = pk_bf16(fmaxf(C1B[2 * v + 8], 0.f), fmaxf(C1B[2 * v + 9], 0.f));
        }
        accA = __builtin_amdgcn_mfma_f32_32x32x16_bf16(a0A.s, B2w0, accA, 0, 0, 0);
        accA = __builtin_amdgcn_mfma_f32_32x32x16_bf16(a1A.s, B2w1, accA, 0, 0, 0);
        accB = __builtin_amdgcn_mfma_f32_32x32x16_bf16(a0B.s, B2w0, accB, 0, 0, 0);
        accB = __builtin_amdgcn_mfma_f32_32x32x16_bf16(a1B.s, B2w1, accB, 0, 0, 0);
    }

    // ---- park partial f (cols<8) in [token][i] layout ----
    if (il < 8) {
        float* fb = &park[wid][0];
#pragma unroll
        for (int r = 0; r < 16; ++r) {
            const int trow = (r & 3) + 8 * (r >> 2) + 4 * hi2;
            fb[trow * 8 + il]        = accA[r];
            fb[(32 + trow) * 8 + il] = accB[r];
        }
    }
    __syncthreads();

    // ---- combine + LN2 + store: one wave per token group ----
    if (q == 0) {
        float fv[8] = {0.f, 0.f, 0.f, 0.f, 0.f, 0.f, 0.f, 0.f};
#pragma unroll
        for (int qq = 0; qq < 4; ++qq) {
            const float* pb = &park[qq * 4 + g][lane * 8];
            const float4 f0 = *reinterpret_cast<const float4*>(pb);
            const float4 f1 = *reinterpret_cast<const float4*>(pb + 4);
            fv[0] += f0.x; fv[1] += f0.y; fv[2] += f0.z; fv[3] += f0.w;
            fv[4] += f1.x; fv[5] += f1.y; fv[6] += f1.z; fv[7] += f1.w;
        }

        float y[8];
#pragma unroll
        for (int j = 0; j < 8; ++j) y[j] = h[j] + fv[j] + b2[j];
        float mean2 = 0.f;
#pragma unroll
        for (int j = 0; j < 8; ++j) mean2 += y[j];
        mean2 *= 0.125f;
        float var2 = 0.f;
#pragma unroll
        for (int j = 0; j < 8; ++j) { float d = y[j] - mean2; var2 = fmaf(d, d, var2); }
        var2 *= 0.125f;
        const float rs2 = rsqrtf(var2 + EPSV);

        float o[8];
#pragma unroll
        for (int j = 0; j < 8; ++j) o[j] = (y[j] - mean2) * rs2 * g2[j] + be2[j];

        float4* op = reinterpret_cast<float4*>(out + (size_t)token * NQ);
        op[0] = make_float4(o[0], o[1], o[2], o[3]);
        op[1] = make_float4(o[4], o[5], o[6], o[7]);
    }
}

extern "C" void kernel_launch(void* const* d_in, const int* in_sizes, int n_in,
                              void* d_out, int out_size, void* d_ws, size_t ws_size,
                              hipStream_t stream) {
    const float* x     = (const float*)d_in[0];
    const float* theta = (const float*)d_in[1];
    const float* phi   = (const float*)d_in[2];
    const float* W1    = (const float*)d_in[3];
    const float* b1    = (const float*)d_in[4];
    const float* W2    = (const float*)d_in[5];
    const float* b2    = (const float*)d_in[6];
    const float* g1    = (const float*)d_in[7];
    const float* be1   = (const float*)d_in[8];
    const float* g2    = (const float*)d_in[9];
    const float* be2   = (const float*)d_in[10];
    float* out = (float*)d_out;

    const int ntok = in_sizes[0] / NQ;   // 65536
    const int grid = ntok / 256;         // 256 blocks x 1024 thr, 1 block/CU

    qtb_kernel<<<grid, 1024, 0, stream>>>(x, theta, phi, W1, b1, W2, b2,
                                          g1, be1, g2, be2, out);
}

// Round 5
// 25.354 us; speedup vs baseline: 9.8604x; 1.0279x over previous
//
#include <hip/hip_runtime.h>
#include <math.h>

#define NQ 8
#define FDIM 2048
#define EPSV 1e-5f

typedef __attribute__((ext_vector_type(8))) short short8v;   // 8 bf16 = 4 VGPR
typedef __attribute__((ext_vector_type(16))) float f32x16;   // 32x32 C/D frag

union PackU { unsigned u[4]; short8v s; };

__device__ __forceinline__ unsigned pk_bf16(float lo, float hi) {
    unsigned r;
    asm("v_cvt_pk_bf16_f32 %0, %1, %2" : "=v"(r) : "v"(lo), "v"(hi));
    return r;
}

// 1024 thr = 16 waves = 4/SIMD. wave wid = q*4+g: token group g (64 tokens),
// f-chunks [q*16, q*16+16). R4 post-mortem: uncapped body needs 132 VGPR but
// cap is 128 -> in-loop spills. R5: park h in LDS during the loop (-8 regs, all
// waves) and replace unroll-2 with explicit 1-deep prefetch (bounded transients).
__launch_bounds__(1024, 1)
__global__ void qtb_kernel(const float* __restrict__ x,
                           const float* __restrict__ theta,
                           const float* __restrict__ phi,
                           const float* __restrict__ W1,
                           const float* __restrict__ b1,
                           const float* __restrict__ W2,
                           const float* __restrict__ b2,
                           const float* __restrict__ g1,
                           const float* __restrict__ be1,
                           const float* __restrict__ g2,
                           const float* __restrict__ be2,
                           float* __restrict__ out)
{
    __shared__ short W1f[64 * 512];    // A-frag order, 64 KB
    __shared__ short W2s[8 * 2056];    // quad-permuted k, ~32 KB
    __shared__ float park[16][512];    // per-wave partial f (64 tok x 8), 32 KB
    __shared__ float hLds[256 * 8];    // h parked across the loop, 8 KB

    const int tid = threadIdx.x;

    // ---- stage W1(+b1) into A-fragment order ----
    for (int k = tid; k < FDIM; k += 1024) {
        const float4 wa = *reinterpret_cast<const float4*>(W1 + (size_t)k * NQ);
        const float4 wb = *reinterpret_cast<const float4*>(W1 + (size_t)k * NQ + 4);
        const float bk = b1[k];
        unsigned* d0 = reinterpret_cast<unsigned*>(&W1f[(k >> 5) * 512 + (k & 31) * 8]);
        unsigned* d1 = reinterpret_cast<unsigned*>(&W1f[(k >> 5) * 512 + ((k & 31) + 32) * 8]);
        d0[0] = pk_bf16(wa.x, wa.y); d0[1] = pk_bf16(wa.z, wa.w);
        d0[2] = pk_bf16(bk, 0.f);    d0[3] = 0u;
        d1[0] = pk_bf16(wb.x, wb.y); d1[1] = pk_bf16(wb.z, wb.w);
        d1[2] = 0u;                  d1[3] = 0u;
    }
    // ---- stage W2 bf16, k permuted within 16-blocks (quad order 0,2,1,3) ----
    for (int idx = tid; idx < 8 * 1024; idx += 1024) {
        const int i = idx >> 10, kp = idx & 1023;
        const int k0 = kp * 2;
        const float2 w = *reinterpret_cast<const float2*>(W2 + (size_t)i * FDIM + k0);
        const int quad = (k0 >> 2) & 3;
        const int posq = (0x3120 >> (quad * 4)) & 0xF;
        const int dcol = (k0 & ~15) | (posq * 4 + (k0 & 3));
        *reinterpret_cast<unsigned*>(&W2s[i * 2056 + dcol]) = pk_bf16(w.x, w.y);
    }
    __syncthreads();

    const int lane = tid & 63;
    const int wid  = tid >> 6;      // 0..15
    const int q    = wid >> 2;      // f-quarter 0..3
    const int g    = wid & 3;       // token group 0..3
    const int hi2  = lane >> 5;
    const int il   = lane & 31;
    const int token = blockIdx.x * 256 + g * 64 + lane;

    // ---- per-token prologue (replicated across the 4 f-quarter waves) ----
    const float4 xa = reinterpret_cast<const float4*>(x + (size_t)token * NQ)[0];
    const float4 xb = reinterpret_cast<const float4*>(x + (size_t)token * NQ)[1];
    float xv[8] = {xa.x, xa.y, xa.z, xa.w, xb.x, xb.y, xb.z, xb.w};

    float c[8];
#pragma unroll
    for (int j = 0; j < 8; ++j) c[j] = cosf(xv[j] + theta[j]);
    float attn[8];
    attn[0] = ((c[1] * c[2]) * (c[3] * c[4])) * ((c[5] * c[6]) * c[7]);
    {
        float p = c[0];
#pragma unroll
        for (int j = 1; j < 8; ++j) { p *= c[j]; attn[j] = p; }
    }
    float s[8];
#pragma unroll
    for (int j = 0; j < 8; ++j) s[j] = xv[j] + attn[j];
    float mean = 0.f;
#pragma unroll
    for (int j = 0; j < 8; ++j) mean += s[j];
    mean *= 0.125f;
    float var = 0.f;
#pragma unroll
    for (int j = 0; j < 8; ++j) { float d = s[j] - mean; var = fmaf(d, d, var); }
    var *= 0.125f;
    const float rs = rsqrtf(var + EPSV);
    float h[8];
#pragma unroll
    for (int j = 0; j < 8; ++j) h[j] = (s[j] - mean) * rs * g1[j] + be1[j];

    float zv[8];
#pragma unroll
    for (int j = 0; j < 8; ++j) zv[j] = cosf(phi[j]) * cosf(h[j]);

    // park h: only the combine wave (q==0) needs it after the loop; writing it
    // to LDS kills h's loop-spanning live range for ALL waves (static alloc).
    if (q == 0) {
        float4* hp = reinterpret_cast<float4*>(&hLds[(g * 64 + lane) * 8]);
        hp[0] = make_float4(h[0], h[1], h[2], h[3]);
        hp[1] = make_float4(h[4], h[5], h[6], h[7]);
    }

    // ---- z B-fragments for both token-subtiles ----
    unsigned zpk[4];
#pragma unroll
    for (int p = 0; p < 4; ++p) zpk[p] = pk_bf16(zv[2 * p], zv[2 * p + 1]);
    unsigned zApk[4], zBpk[4];
#pragma unroll
    for (int p = 0; p < 4; ++p) {
        zApk[p] = (unsigned)__shfl((int)zpk[p], il);
        zBpk[p] = (unsigned)__shfl((int)zpk[p], 32 + il);
    }
    const unsigned biasv = 0x00003f80u;  // bf16(1.0) low half
    PackU b1A, b1B;
    b1A.u[0] = hi2 ? zApk[2] : zApk[0];
    b1A.u[1] = hi2 ? zApk[3] : zApk[1];
    b1A.u[2] = hi2 ? 0u : biasv;
    b1A.u[3] = 0u;
    b1B.u[0] = hi2 ? zBpk[2] : zBpk[0];
    b1B.u[1] = hi2 ? zBpk[3] : zBpk[1];
    b1B.u[2] = hi2 ? 0u : biasv;
    b1B.u[3] = 0u;

    f32x16 zeroC;
#pragma unroll
    for (int e = 0; e < 16; ++e) zeroC[e] = 0.f;
    f32x16 accA = zeroC, accB = zeroC;

    const int ir = il & 7;

    // ---- f-chunk loop: 16 chunks of 32 f, 1-deep explicit prefetch ----
    const short* W1base = &W1f[(q * 16) * 512 + lane * 8];
    const short* w2base = &W2s[ir * 2056 + (q * 16) * 32 + hi2 * 8];

    short8v A1n = *reinterpret_cast<const short8v*>(W1base);
    short8v B0n = *reinterpret_cast<const short8v*>(w2base);
    short8v B1n = *reinterpret_cast<const short8v*>(w2base + 16);

#pragma unroll 1
    for (int t = 0; t < 16; ++t) {
        const short8v A1 = A1n, B0 = B0n, B1 = B1n;
        const int tn = (t + 1) & 15;          // wrap: always-valid LDS prefetch
        A1n = *reinterpret_cast<const short8v*>(W1base + tn * 512);
        B0n = *reinterpret_cast<const short8v*>(w2base + tn * 32);
        B1n = *reinterpret_cast<const short8v*>(w2base + tn * 32 + 16);

        f32x16 C1A = __builtin_amdgcn_mfma_f32_32x32x16_bf16(A1, b1A.s, zeroC, 0, 0, 0);
        PackU a0A, a1A;
#pragma unroll
        for (int v = 0; v < 4; ++v) {
            a0A.u[v] = pk_bf16(fmaxf(C1A[2 * v], 0.f),     fmaxf(C1A[2 * v + 1], 0.f));
            a1A.u[v] = pk_bf16(fmaxf(C1A[2 * v + 8], 0.f), fmaxf(C1A[2 * v + 9], 0.f));
        }
        f32x16 C1B = __builtin_amdgcn_mfma_f32_32x32x16_bf16(A1, b1B.s, zeroC, 0, 0, 0);
        PackU a0B, a1B;
#pragma unroll
        for (int v = 0; v < 4; ++v) {
            a0B.u[v] = pk_bf16(fmaxf(C1B[2 * v], 0.f),     fmaxf(C1B[2 * v + 1], 0.f));
            a1B.u[v] = pk_bf16(fmaxf(C1B[2 * v + 8], 0.f), fmaxf(C1B[2 * v + 9], 0.f));
        }
        accA = __builtin_amdgcn_mfma_f32_32x32x16_bf16(a0A.s, B0, accA, 0, 0, 0);
        accA = __builtin_amdgcn_mfma_f32_32x32x16_bf16(a1A.s, B1, accA, 0, 0, 0);
        accB = __builtin_amdgcn_mfma_f32_32x32x16_bf16(a0B.s, B0, accB, 0, 0, 0);
        accB = __builtin_amdgcn_mfma_f32_32x32x16_bf16(a1B.s, B1, accB, 0, 0, 0);
    }

    // ---- park partial f (cols<8) in [token][i] layout ----
    if (il < 8) {
        float* fb = &park[wid][0];
#pragma unroll
        for (int r = 0; r < 16; ++r) {
            const int trow = (r & 3) + 8 * (r >> 2) + 4 * hi2;
            fb[trow * 8 + il]        = accA[r];
            fb[(32 + trow) * 8 + il] = accB[r];
        }
    }
    __syncthreads();

    // ---- combine + LN2 + store: one wave per token group ----
    if (q == 0) {
        float fv[8] = {0.f, 0.f, 0.f, 0.f, 0.f, 0.f, 0.f, 0.f};
#pragma unroll
        for (int qq = 0; qq < 4; ++qq) {
            const float* pb = &park[qq * 4 + g][lane * 8];
            const float4 f0 = *reinterpret_cast<const float4*>(pb);
            const float4 f1 = *reinterpret_cast<const float4*>(pb + 4);
            fv[0] += f0.x; fv[1] += f0.y; fv[2] += f0.z; fv[3] += f0.w;
            fv[4] += f1.x; fv[5] += f1.y; fv[6] += f1.z; fv[7] += f1.w;
        }

        const float4 h0 = reinterpret_cast<const float4*>(&hLds[(g * 64 + lane) * 8])[0];
        const float4 h1 = reinterpret_cast<const float4*>(&hLds[(g * 64 + lane) * 8])[1];
        const float hv[8] = {h0.x, h0.y, h0.z, h0.w, h1.x, h1.y, h1.z, h1.w};

        float y[8];
#pragma unroll
        for (int j = 0; j < 8; ++j) y[j] = hv[j] + fv[j] + b2[j];
        float mean2 = 0.f;
#pragma unroll
        for (int j = 0; j < 8; ++j) mean2 += y[j];
        mean2 *= 0.125f;
        float var2 = 0.f;
#pragma unroll
        for (int j = 0; j < 8; ++j) { float d = y[j] - mean2; var2 = fmaf(d, d, var2); }
        var2 *= 0.125f;
        const float rs2 = rsqrtf(var2 + EPSV);

        float o[8];
#pragma unroll
        for (int j = 0; j < 8; ++j) o[j] = (y[j] - mean2) * rs2 * g2[j] + be2[j];

        float4* op = reinterpret_cast<float4*>(out + (size_t)token * NQ);
        op[0] = make_float4(o[0], o[1], o[2], o[3]);
        op[1] = make_float4(o[4], o[5], o[6], o[7]);
    }
}

extern "C" void kernel_launch(void* const* d_in, const int* in_sizes, int n_in,
                              void* d_out, int out_size, void* d_ws, size_t ws_size,
                              hipStream_t stream) {
    const float* x     = (const float*)d_in[0];
    const float* theta = (const float*)d_in[1];
    const float* phi   = (const float*)d_in[2];
    const float* W1    = (const float*)d_in[3];
    const float* b1    = (const float*)d_in[4];
    const float* W2    = (const float*)d_in[5];
    const float* b2    = (const float*)d_in[6];
    const float* g1    = (const float*)d_in[7];
    const float* be1   = (const float*)d_in[8];
    const float* g2    = (const float*)d_in[9];
    const float* be2   = (const float*)d_in[10];
    float* out = (float*)d_out;

    const int ntok = in_sizes[0] / NQ;   // 65536
    const int grid = ntok / 256;         // 256 blocks x 1024 thr, 1 block/CU

    qtb_kernel<<<grid, 1024, 0, stream>>>(x, theta, phi, W1, b1, W2, b2,
                                          g1, be1, g2, be2, out);
}

// Round 6
// 23.575 us; speedup vs baseline: 10.6044x; 1.0755x over previous
//
#include <hip/hip_runtime.h>
#include <math.h>

#define NQ 8
#define FDIM 2048
#define EPSV 1e-5f

typedef __attribute__((ext_vector_type(8))) short short8v;   // 8 bf16 = 4 VGPR
typedef __attribute__((ext_vector_type(16))) float f32x16;   // 32x32 C/D frag

__device__ __forceinline__ unsigned pk_bf16(float lo, float hi) {
    unsigned r;
    asm("v_cvt_pk_bf16_f32 %0, %1, %2" : "=v"(r) : "v"(lo), "v"(hi));
    return r;
}

__device__ __forceinline__ short8v pack4(unsigned a, unsigned b, unsigned c, unsigned d) {
    uint4 w; w.x = a; w.y = b; w.z = c; w.w = d;
    return __builtin_bit_cast(short8v, w);
}

// 768 thr = 12 waves = 3/SIMD -> VGPR cap 170 (vs 128 at 16 waves): room for the
// ~132-reg body, testing the R4/R5 spill hypothesis while keeping multi-wave.
// wave wid = q*4+g: token group g (64 tokens), f-chunk range q (21/21/22 of 64).
// GEMM1 contraction (NQ+bias) is inside one MFMA -> relu exact under f-split;
// chunk loop is GEMM2's contraction -> partials sum linearly (parked in LDS).
__launch_bounds__(768, 3)
__global__ void qtb_kernel(const float* __restrict__ x,
                           const float* __restrict__ theta,
                           const float* __restrict__ phi,
                           const float* __restrict__ W1,
                           const float* __restrict__ b1,
                           const float* __restrict__ W2,
                           const float* __restrict__ b2,
                           const float* __restrict__ g1,
                           const float* __restrict__ be1,
                           const float* __restrict__ g2,
                           const float* __restrict__ be2,
                           float* __restrict__ out)
{
    __shared__ short W1f[64 * 512];    // A-frag order, 64 KB
    __shared__ short W2s[8 * 2056];    // quad-permuted k, ~32 KB
    __shared__ float park[12][512];    // per-wave partial f (64 tok x 8), 24 KB
    __shared__ float hLds[256 * 8];    // h parked across the loop, 8 KB

    const int tid = threadIdx.x;

    // ---- stage W1(+b1) into A-fragment order ----
    for (int k = tid; k < FDIM; k += 768) {
        const float4 wa = *reinterpret_cast<const float4*>(W1 + (size_t)k * NQ);
        const float4 wb = *reinterpret_cast<const float4*>(W1 + (size_t)k * NQ + 4);
        const float bk = b1[k];
        unsigned* d0 = reinterpret_cast<unsigned*>(&W1f[(k >> 5) * 512 + (k & 31) * 8]);
        unsigned* d1 = reinterpret_cast<unsigned*>(&W1f[(k >> 5) * 512 + ((k & 31) + 32) * 8]);
        d0[0] = pk_bf16(wa.x, wa.y); d0[1] = pk_bf16(wa.z, wa.w);
        d0[2] = pk_bf16(bk, 0.f);    d0[3] = 0u;
        d1[0] = pk_bf16(wb.x, wb.y); d1[1] = pk_bf16(wb.z, wb.w);
        d1[2] = 0u;                  d1[3] = 0u;
    }
    // ---- stage W2 bf16, k permuted within 16-blocks (quad order 0,2,1,3) ----
    for (int idx = tid; idx < 8 * 1024; idx += 768) {
        const int i = idx >> 10, kp = idx & 1023;
        const int k0 = kp * 2;
        const float2 w = *reinterpret_cast<const float2*>(W2 + (size_t)i * FDIM + k0);
        const int quad = (k0 >> 2) & 3;
        const int posq = (0x3120 >> (quad * 4)) & 0xF;
        const int dcol = (k0 & ~15) | (posq * 4 + (k0 & 3));
        *reinterpret_cast<unsigned*>(&W2s[i * 2056 + dcol]) = pk_bf16(w.x, w.y);
    }
    __syncthreads();

    const int lane = tid & 63;
    const int wid  = tid >> 6;      // 0..11
    const int q    = wid >> 2;      // f-third 0..2
    const int g    = wid & 3;       // token group 0..3
    const int hi2  = lane >> 5;
    const int il   = lane & 31;
    const int token = blockIdx.x * 256 + g * 64 + lane;

    // ---- per-token prologue (replicated across the 3 f-third waves) ----
    const float4 xa = reinterpret_cast<const float4*>(x + (size_t)token * NQ)[0];
    const float4 xb = reinterpret_cast<const float4*>(x + (size_t)token * NQ)[1];
    float xv[8] = {xa.x, xa.y, xa.z, xa.w, xb.x, xb.y, xb.z, xb.w};

    float c[8];
#pragma unroll
    for (int j = 0; j < 8; ++j) c[j] = __cosf(xv[j] + theta[j]);
    float attn[8];
    attn[0] = ((c[1] * c[2]) * (c[3] * c[4])) * ((c[5] * c[6]) * c[7]);
    {
        float p = c[0];
#pragma unroll
        for (int j = 1; j < 8; ++j) { p *= c[j]; attn[j] = p; }
    }
    float s[8];
#pragma unroll
    for (int j = 0; j < 8; ++j) s[j] = xv[j] + attn[j];
    float mean = 0.f;
#pragma unroll
    for (int j = 0; j < 8; ++j) mean += s[j];
    mean *= 0.125f;
    float var = 0.f;
#pragma unroll
    for (int j = 0; j < 8; ++j) { float d = s[j] - mean; var = fmaf(d, d, var); }
    var *= 0.125f;
    const float rs = rsqrtf(var + EPSV);
    float h[8];
#pragma unroll
    for (int j = 0; j < 8; ++j) h[j] = (s[j] - mean) * rs * g1[j] + be1[j];

    float zv[8];
#pragma unroll
    for (int j = 0; j < 8; ++j) zv[j] = __cosf(phi[j]) * __cosf(h[j]);

    // park h: only the combine waves (q==0) need it after the loop; LDS-parking
    // kills h's loop-spanning live range for ALL waves (static alloc).
    if (q == 0) {
        float4* hp = reinterpret_cast<float4*>(&hLds[(g * 64 + lane) * 8]);
        hp[0] = make_float4(h[0], h[1], h[2], h[3]);
        hp[1] = make_float4(h[4], h[5], h[6], h[7]);
    }

    // ---- z B-fragments for both token-subtiles ----
    unsigned zpk[4];
#pragma unroll
    for (int p = 0; p < 4; ++p) zpk[p] = pk_bf16(zv[2 * p], zv[2 * p + 1]);
    unsigned zApk[4], zBpk[4];
#pragma unroll
    for (int p = 0; p < 4; ++p) {
        zApk[p] = (unsigned)__shfl((int)zpk[p], il);
        zBpk[p] = (unsigned)__shfl((int)zpk[p], 32 + il);
    }
    const unsigned biasv = 0x00003f80u;  // bf16(1.0) low half
    const short8v b1A = pack4(hi2 ? zApk[2] : zApk[0],
                              hi2 ? zApk[3] : zApk[1],
                              hi2 ? 0u : biasv, 0u);
    const short8v b1B = pack4(hi2 ? zBpk[2] : zBpk[0],
                              hi2 ? zBpk[3] : zBpk[1],
                              hi2 ? 0u : biasv, 0u);

    f32x16 zeroC;
#pragma unroll
    for (int e = 0; e < 16; ++e) zeroC[e] = 0.f;
    f32x16 accA = zeroC, accB = zeroC;

    const int ir = il & 7;

    // ---- f-chunk loop: third q handles [q*21, q*21+21(+1 for q=2)) ----
    const int lo = q * 21;
    const int hi = (q == 2) ? 64 : lo + 21;

#pragma unroll 2
    for (int cc = lo; cc < hi; ++cc) {
        const short8v A1 = *reinterpret_cast<const short8v*>(&W1f[cc * 512 + lane * 8]);
        const short* w2base = &W2s[ir * 2056 + cc * 32];
        const short8v B0 = *reinterpret_cast<const short8v*>(w2base + hi2 * 8);
        const short8v B1 = *reinterpret_cast<const short8v*>(w2base + 16 + hi2 * 8);

        f32x16 C1A = __builtin_amdgcn_mfma_f32_32x32x16_bf16(A1, b1A, zeroC, 0, 0, 0);
        const short8v a0A = pack4(
            pk_bf16(fmaxf(C1A[0], 0.f), fmaxf(C1A[1], 0.f)),
            pk_bf16(fmaxf(C1A[2], 0.f), fmaxf(C1A[3], 0.f)),
            pk_bf16(fmaxf(C1A[4], 0.f), fmaxf(C1A[5], 0.f)),
            pk_bf16(fmaxf(C1A[6], 0.f), fmaxf(C1A[7], 0.f)));
        const short8v a1A = pack4(
            pk_bf16(fmaxf(C1A[8], 0.f),  fmaxf(C1A[9], 0.f)),
            pk_bf16(fmaxf(C1A[10], 0.f), fmaxf(C1A[11], 0.f)),
            pk_bf16(fmaxf(C1A[12], 0.f), fmaxf(C1A[13], 0.f)),
            pk_bf16(fmaxf(C1A[14], 0.f), fmaxf(C1A[15], 0.f)));

        f32x16 C1B = __builtin_amdgcn_mfma_f32_32x32x16_bf16(A1, b1B, zeroC, 0, 0, 0);
        const short8v a0B = pack4(
            pk_bf16(fmaxf(C1B[0], 0.f), fmaxf(C1B[1], 0.f)),
            pk_bf16(fmaxf(C1B[2], 0.f), fmaxf(C1B[3], 0.f)),
            pk_bf16(fmaxf(C1B[4], 0.f), fmaxf(C1B[5], 0.f)),
            pk_bf16(fmaxf(C1B[6], 0.f), fmaxf(C1B[7], 0.f)));
        const short8v a1B = pack4(
            pk_bf16(fmaxf(C1B[8], 0.f),  fmaxf(C1B[9], 0.f)),
            pk_bf16(fmaxf(C1B[10], 0.f), fmaxf(C1B[11], 0.f)),
            pk_bf16(fmaxf(C1B[12], 0.f), fmaxf(C1B[13], 0.f)),
            pk_bf16(fmaxf(C1B[14], 0.f), fmaxf(C1B[15], 0.f)));

        accA = __builtin_amdgcn_mfma_f32_32x32x16_bf16(a0A, B0, accA, 0, 0, 0);
        accA = __builtin_amdgcn_mfma_f32_32x32x16_bf16(a1A, B1, accA, 0, 0, 0);
        accB = __builtin_amdgcn_mfma_f32_32x32x16_bf16(a0B, B0, accB, 0, 0, 0);
        accB = __builtin_amdgcn_mfma_f32_32x32x16_bf16(a1B, B1, accB, 0, 0, 0);
    }

    // ---- park partial f (cols<8) in [token][i] layout ----
    if (il < 8) {
        float* fb = &park[wid][0];
#pragma unroll
        for (int r = 0; r < 16; ++r) {
            const int trow = (r & 3) + 8 * (r >> 2) + 4 * hi2;
            fb[trow * 8 + il]        = accA[r];
            fb[(32 + trow) * 8 + il] = accB[r];
        }
    }
    __syncthreads();

    // ---- combine + LN2 + store: one wave per token group ----
    if (q == 0) {
        float fv[8] = {0.f, 0.f, 0.f, 0.f, 0.f, 0.f, 0.f, 0.f};
#pragma unroll
        for (int qq = 0; qq < 3; ++qq) {
            const float* pb = &park[qq * 4 + g][lane * 8];
            const float4 f0 = *reinterpret_cast<const float4*>(pb);
            const float4 f1 = *reinterpret_cast<const float4*>(pb + 4);
            fv[0] += f0.x; fv[1] += f0.y; fv[2] += f0.z; fv[3] += f0.w;
            fv[4] += f1.x; fv[5] += f1.y; fv[6] += f1.z; fv[7] += f1.w;
        }

        const float4 h0 = reinterpret_cast<const float4*>(&hLds[(g * 64 + lane) * 8])[0];
        const float4 h1 = reinterpret_cast<const float4*>(&hLds[(g * 64 + lane) * 8])[1];
        const float hv[8] = {h0.x, h0.y, h0.z, h0.w, h1.x, h1.y, h1.z, h1.w};

        float y[8];
#pragma unroll
        for (int j = 0; j < 8; ++j) y[j] = hv[j] + fv[j] + b2[j];
        float mean2 = 0.f;
#pragma unroll
        for (int j = 0; j < 8; ++j) mean2 += y[j];
        mean2 *= 0.125f;
        float var2 = 0.f;
#pragma unroll
        for (int j = 0; j < 8; ++j) { float d = y[j] - mean2; var2 = fmaf(d, d, var2); }
        var2 *= 0.125f;
        const float rs2 = rsqrtf(var2 + EPSV);

        float o[8];
#pragma unroll
        for (int j = 0; j < 8; ++j) o[j] = (y[j] - mean2) * rs2 * g2[j] + be2[j];

        float4* op = reinterpret_cast<float4*>(out + (size_t)token * NQ);
        op[0] = make_float4(o[0], o[1], o[2], o[3]);
        op[1] = make_float4(o[4], o[5], o[6], o[7]);
    }
}

extern "C" void kernel_launch(void* const* d_in, const int* in_sizes, int n_in,
                              void* d_out, int out_size, void* d_ws, size_t ws_size,
                              hipStream_t stream) {
    const float* x     = (const float*)d_in[0];
    const float* theta = (const float*)d_in[1];
    const float* phi   = (const float*)d_in[2];
    const float* W1    = (const float*)d_in[3];
    const float* b1    = (const float*)d_in[4];
    const float* W2    = (const float*)d_in[5];
    const float* b2    = (const float*)d_in[6];
    const float* g1    = (const float*)d_in[7];
    const float* be1   = (const float*)d_in[8];
    const float* g2    = (const float*)d_in[9];
    const float* be2   = (const float*)d_in[10];
    float* out = (float*)d_out;

    const int ntok = in_sizes[0] / NQ;   // 65536
    const int grid = ntok / 256;         // 256 blocks x 768 thr, 1 block/CU

    qtb_kernel<<<grid, 768, 0, stream>>>(x, theta, phi, W1, b1, W2, b2,
                                         g1, be1, g2, be2, out);
}

// Round 7
// 22.601 us; speedup vs baseline: 11.0612x; 1.0431x over previous
//
#include <hip/hip_runtime.h>
#include <math.h>

#define NQ 8
#define FDIM 2048
#define EPSV 1e-5f

typedef __attribute__((ext_vector_type(8))) short short8v;   // 8 bf16 = 4 VGPR
typedef __attribute__((ext_vector_type(16))) float f32x16;   // 32x32 C/D frag

__device__ __forceinline__ unsigned pk_bf16(float lo, float hi) {
    unsigned r;
    asm("v_cvt_pk_bf16_f32 %0, %1, %2" : "=v"(r) : "v"(lo), "v"(hi));
    return r;
}

__device__ __forceinline__ short8v pack4(unsigned a, unsigned b, unsigned c, unsigned d) {
    uint4 w; w.x = a; w.y = b; w.z = c; w.w = d;
    return __builtin_bit_cast(short8v, w);
}

// R7: software-pipeline C1 across iterations. R3/R6 scaling showed a
// ~1700-2650 cyc per-chunk dependency chain (ds->C1 MFMA->repack->acc) that
// 3 waves/SIMD cannot hide. Iteration t now: repack C1(t) -> issue C1(t+1)
// -> acc(t) -> load tile(t+2). Manual 2x unroll, named double buffers.
#define ITER(AUSE, ALOAD, B0USE, B1USE, C2IDX)                                      \
  {                                                                                 \
    const short8v a0A = pack4(                                                      \
        pk_bf16(fmaxf(C1A[0], 0.f),  fmaxf(C1A[1], 0.f)),                           \
        pk_bf16(fmaxf(C1A[2], 0.f),  fmaxf(C1A[3], 0.f)),                           \
        pk_bf16(fmaxf(C1A[4], 0.f),  fmaxf(C1A[5], 0.f)),                           \
        pk_bf16(fmaxf(C1A[6], 0.f),  fmaxf(C1A[7], 0.f)));                          \
    const short8v a1A = pack4(                                                      \
        pk_bf16(fmaxf(C1A[8], 0.f),  fmaxf(C1A[9], 0.f)),                           \
        pk_bf16(fmaxf(C1A[10], 0.f), fmaxf(C1A[11], 0.f)),                          \
        pk_bf16(fmaxf(C1A[12], 0.f), fmaxf(C1A[13], 0.f)),                          \
        pk_bf16(fmaxf(C1A[14], 0.f), fmaxf(C1A[15], 0.f)));                         \
    C1A = __builtin_amdgcn_mfma_f32_32x32x16_bf16(AUSE, b1A, zeroC, 0, 0, 0);       \
    const short8v a0B = pack4(                                                      \
        pk_bf16(fmaxf(C1B[0], 0.f),  fmaxf(C1B[1], 0.f)),                           \
        pk_bf16(fmaxf(C1B[2], 0.f),  fmaxf(C1B[3], 0.f)),                           \
        pk_bf16(fmaxf(C1B[4], 0.f),  fmaxf(C1B[5], 0.f)),                           \
        pk_bf16(fmaxf(C1B[6], 0.f),  fmaxf(C1B[7], 0.f)));                          \
    const short8v a1B = pack4(                                                      \
        pk_bf16(fmaxf(C1B[8], 0.f),  fmaxf(C1B[9], 0.f)),                           \
        pk_bf16(fmaxf(C1B[10], 0.f), fmaxf(C1B[11], 0.f)),                          \
        pk_bf16(fmaxf(C1B[12], 0.f), fmaxf(C1B[13], 0.f)),                          \
        pk_bf16(fmaxf(C1B[14], 0.f), fmaxf(C1B[15], 0.f)));                         \
    C1B = __builtin_amdgcn_mfma_f32_32x32x16_bf16(AUSE, b1B, zeroC, 0, 0, 0);       \
    accA = __builtin_amdgcn_mfma_f32_32x32x16_bf16(a0A, B0USE, accA, 0, 0, 0);      \
    accA = __builtin_amdgcn_mfma_f32_32x32x16_bf16(a1A, B1USE, accA, 0, 0, 0);      \
    accB = __builtin_amdgcn_mfma_f32_32x32x16_bf16(a0B, B0USE, accB, 0, 0, 0);      \
    accB = __builtin_amdgcn_mfma_f32_32x32x16_bf16(a1B, B1USE, accB, 0, 0, 0);      \
    ALOAD = *reinterpret_cast<const short8v*>(W1p + (C2IDX) * 512);                 \
    B0USE = *reinterpret_cast<const short8v*>(W2p + (C2IDX) * 32);                  \
    B1USE = *reinterpret_cast<const short8v*>(W2p + (C2IDX) * 32 + 16);             \
  }

__launch_bounds__(768, 3)
__global__ void qtb_kernel(const float* __restrict__ x,
                           const float* __restrict__ theta,
                           const float* __restrict__ phi,
                           const float* __restrict__ W1,
                           const float* __restrict__ b1,
                           const float* __restrict__ W2,
                           const float* __restrict__ b2,
                           const float* __restrict__ g1,
                           const float* __restrict__ be1,
                           const float* __restrict__ g2,
                           const float* __restrict__ be2,
                           float* __restrict__ out)
{
    __shared__ short W1f[64 * 512];    // A-frag order, 64 KB
    __shared__ short W2s[8 * 2056];    // quad-permuted k, ~32 KB
    __shared__ float park[12][512];    // per-wave partial f, 24 KB
    __shared__ float hLds[256 * 8];    // h parked across the loop, 8 KB

    const int tid = threadIdx.x;

    // ---- stage W1(+b1) into A-fragment order ----
    for (int k = tid; k < FDIM; k += 768) {
        const float4 wa = *reinterpret_cast<const float4*>(W1 + (size_t)k * NQ);
        const float4 wb = *reinterpret_cast<const float4*>(W1 + (size_t)k * NQ + 4);
        const float bk = b1[k];
        unsigned* d0 = reinterpret_cast<unsigned*>(&W1f[(k >> 5) * 512 + (k & 31) * 8]);
        unsigned* d1 = reinterpret_cast<unsigned*>(&W1f[(k >> 5) * 512 + ((k & 31) + 32) * 8]);
        d0[0] = pk_bf16(wa.x, wa.y); d0[1] = pk_bf16(wa.z, wa.w);
        d0[2] = pk_bf16(bk, 0.f);    d0[3] = 0u;
        d1[0] = pk_bf16(wb.x, wb.y); d1[1] = pk_bf16(wb.z, wb.w);
        d1[2] = 0u;                  d1[3] = 0u;
    }
    // ---- stage W2 bf16, k permuted within 16-blocks (quad order 0,2,1,3) ----
    for (int idx = tid; idx < 8 * 1024; idx += 768) {
        const int i = idx >> 10, kp = idx & 1023;
        const int k0 = kp * 2;
        const float2 w = *reinterpret_cast<const float2*>(W2 + (size_t)i * FDIM + k0);
        const int quad = (k0 >> 2) & 3;
        const int posq = (0x3120 >> (quad * 4)) & 0xF;
        const int dcol = (k0 & ~15) | (posq * 4 + (k0 & 3));
        *reinterpret_cast<unsigned*>(&W2s[i * 2056 + dcol]) = pk_bf16(w.x, w.y);
    }
    __syncthreads();

    const int lane = tid & 63;
    const int wid  = tid >> 6;      // 0..11
    const int q    = wid >> 2;      // f-third 0..2
    const int g    = wid & 3;       // token group 0..3
    const int hi2  = lane >> 5;
    const int il   = lane & 31;
    const int token = blockIdx.x * 256 + g * 64 + lane;

    // ---- per-token prologue ----
    const float4 xa = reinterpret_cast<const float4*>(x + (size_t)token * NQ)[0];
    const float4 xb = reinterpret_cast<const float4*>(x + (size_t)token * NQ)[1];
    float xv[8] = {xa.x, xa.y, xa.z, xa.w, xb.x, xb.y, xb.z, xb.w};

    float c[8];
#pragma unroll
    for (int j = 0; j < 8; ++j) c[j] = __cosf(xv[j] + theta[j]);
    float attn[8];
    attn[0] = ((c[1] * c[2]) * (c[3] * c[4])) * ((c[5] * c[6]) * c[7]);
    {
        float p = c[0];
#pragma unroll
        for (int j = 1; j < 8; ++j) { p *= c[j]; attn[j] = p; }
    }
    float s[8];
#pragma unroll
    for (int j = 0; j < 8; ++j) s[j] = xv[j] + attn[j];
    float mean = 0.f;
#pragma unroll
    for (int j = 0; j < 8; ++j) mean += s[j];
    mean *= 0.125f;
    float var = 0.f;
#pragma unroll
    for (int j = 0; j < 8; ++j) { float d = s[j] - mean; var = fmaf(d, d, var); }
    var *= 0.125f;
    const float rs = rsqrtf(var + EPSV);
    float h[8];
#pragma unroll
    for (int j = 0; j < 8; ++j) h[j] = (s[j] - mean) * rs * g1[j] + be1[j];

    float zv[8];
#pragma unroll
    for (int j = 0; j < 8; ++j) zv[j] = __cosf(phi[j]) * __cosf(h[j]);

    // park h in LDS (combine waves reload it after the loop)
    if (q == 0) {
        float4* hp = reinterpret_cast<float4*>(&hLds[(g * 64 + lane) * 8]);
        hp[0] = make_float4(h[0], h[1], h[2], h[3]);
        hp[1] = make_float4(h[4], h[5], h[6], h[7]);
    }

    // ---- z B-fragments for both token-subtiles ----
    unsigned zpk[4];
#pragma unroll
    for (int p = 0; p < 4; ++p) zpk[p] = pk_bf16(zv[2 * p], zv[2 * p + 1]);
    unsigned zApk[4], zBpk[4];
#pragma unroll
    for (int p = 0; p < 4; ++p) {
        zApk[p] = (unsigned)__shfl((int)zpk[p], il);
        zBpk[p] = (unsigned)__shfl((int)zpk[p], 32 + il);
    }
    const unsigned biasv = 0x00003f80u;  // bf16(1.0) low half
    const short8v b1A = pack4(hi2 ? zApk[2] : zApk[0],
                              hi2 ? zApk[3] : zApk[1],
                              hi2 ? 0u : biasv, 0u);
    const short8v b1B = pack4(hi2 ? zBpk[2] : zBpk[0],
                              hi2 ? zBpk[3] : zBpk[1],
                              hi2 ? 0u : biasv, 0u);

    f32x16 zeroC;
#pragma unroll
    for (int e = 0; e < 16; ++e) zeroC[e] = 0.f;
    f32x16 accA = zeroC, accB = zeroC;

    const int ir = il & 7;
    const int n  = (q == 2) ? 22 : 21;
    const int lo = q * 21;

    const short* W1p = &W1f[lane * 8];               // + chunk*512
    const short* W2p = &W2s[ir * 2056 + hi2 * 8];    // + chunk*32 (+16)

    // ---- pipeline prologue: C1 gen 0 in flight; tiles 0 and 1 resident ----
    short8v A1a = *reinterpret_cast<const short8v*>(W1p + lo * 512);
    short8v B0a = *reinterpret_cast<const short8v*>(W2p + lo * 32);
    short8v B1a = *reinterpret_cast<const short8v*>(W2p + lo * 32 + 16);
    f32x16 C1A = __builtin_amdgcn_mfma_f32_32x32x16_bf16(A1a, b1A, zeroC, 0, 0, 0);
    f32x16 C1B = __builtin_amdgcn_mfma_f32_32x32x16_bf16(A1a, b1B, zeroC, 0, 0, 0);
    short8v A1b = *reinterpret_cast<const short8v*>(W1p + (lo + 1) * 512);
    short8v B0b = *reinterpret_cast<const short8v*>(W2p + (lo + 1) * 32);
    short8v B1b = *reinterpret_cast<const short8v*>(W2p + (lo + 1) * 32 + 16);

    // ---- main loop: pairs of iterations with named double buffers ----
    int t = 0;
#pragma unroll 1
    for (; t + 1 < n; t += 2) {
        int c2 = t + 2; if (c2 >= n) c2 -= n; c2 += lo;   // wrap: valid LDS, dead compute
        int c3 = t + 3; if (c3 >= n) c3 -= n; c3 += lo;
        ITER(A1b, A1a, B0a, B1a, c2);   // even: uses A(t+1), B(t); loads tile t+2
        ITER(A1a, A1b, B0b, B1b, c3);   // odd:  uses A(t+2), B(t+1); loads tile t+3
    }
    if (t < n) {                         // tail (n odd)
        int c2 = t + 2 - n + lo;
        ITER(A1b, A1a, B0a, B1a, c2);
    }

    // ---- park partial f (cols<8) in [token][i] layout ----
    if (il < 8) {
        float* fb = &park[wid][0];
#pragma unroll
        for (int r = 0; r < 16; ++r) {
            const int trow = (r & 3) + 8 * (r >> 2) + 4 * hi2;
            fb[trow * 8 + il]        = accA[r];
            fb[(32 + trow) * 8 + il] = accB[r];
        }
    }
    __syncthreads();

    // ---- combine + LN2 + store: one wave per token group ----
    if (q == 0) {
        float fv[8] = {0.f, 0.f, 0.f, 0.f, 0.f, 0.f, 0.f, 0.f};
#pragma unroll
        for (int qq = 0; qq < 3; ++qq) {
            const float* pb = &park[qq * 4 + g][lane * 8];
            const float4 f0 = *reinterpret_cast<const float4*>(pb);
            const float4 f1 = *reinterpret_cast<const float4*>(pb + 4);
            fv[0] += f0.x; fv[1] += f0.y; fv[2] += f0.z; fv[3] += f0.w;
            fv[4] += f1.x; fv[5] += f1.y; fv[6] += f1.z; fv[7] += f1.w;
        }

        const float4 h0 = reinterpret_cast<const float4*>(&hLds[(g * 64 + lane) * 8])[0];
        const float4 h1 = reinterpret_cast<const float4*>(&hLds[(g * 64 + lane) * 8])[1];
        const float hv[8] = {h0.x, h0.y, h0.z, h0.w, h1.x, h1.y, h1.z, h1.w};

        float y[8];
#pragma unroll
        for (int j = 0; j < 8; ++j) y[j] = hv[j] + fv[j] + b2[j];
        float mean2 = 0.f;
#pragma unroll
        for (int j = 0; j < 8; ++j) mean2 += y[j];
        mean2 *= 0.125f;
        float var2 = 0.f;
#pragma unroll
        for (int j = 0; j < 8; ++j) { float d = y[j] - mean2; var2 = fmaf(d, d, var2); }
        var2 *= 0.125f;
        const float rs2 = rsqrtf(var2 + EPSV);

        float o[8];
#pragma unroll
        for (int j = 0; j < 8; ++j) o[j] = (y[j] - mean2) * rs2 * g2[j] + be2[j];

        float4* op = reinterpret_cast<float4*>(out + (size_t)token * NQ);
        op[0] = make_float4(o[0], o[1], o[2], o[3]);
        op[1] = make_float4(o[4], o[5], o[6], o[7]);
    }
}

extern "C" void kernel_launch(void* const* d_in, const int* in_sizes, int n_in,
                              void* d_out, int out_size, void* d_ws, size_t ws_size,
                              hipStream_t stream) {
    const float* x     = (const float*)d_in[0];
    const float* theta = (const float*)d_in[1];
    const float* phi   = (const float*)d_in[2];
    const float* W1    = (const float*)d_in[3];
    const float* b1    = (const float*)d_in[4];
    const float* W2    = (const float*)d_in[5];
    const float* b2    = (const float*)d_in[6];
    const float* g1    = (const float*)d_in[7];
    const float* be1   = (const float*)d_in[8];
    const float* g2    = (const float*)d_in[9];
    const float* be2   = (const float*)d_in[10];
    float* out = (float*)d_out;

    const int ntok = in_sizes[0] / NQ;   // 65536
    const int grid = ntok / 256;         // 256 blocks x 768 thr, 1 block/CU

    qtb_kernel<<<grid, 768, 0, stream>>>(x, theta, phi, W1, b1, W2, b2,
                                         g1, be1, g2, be2, out);
}